// Round 13
// baseline (158.493 us; speedup 1.0000x reference)
//
#include <hip/hip_runtime.h>

// KNN k-th smallest distance — single MFMA pass (per-subset TOP-2) + select.
// dist = sqrt(2 - 2*dot(zn,rn)); sorted(dist)[k] == (k+1)-th LARGEST dot.
//  1) normalize_bf16: fused z+ref rows -> L2-normalized bf16
//  2) knn_maxes:  MFMA dots (r10 known-good 8-wave/256q body), epilogue now
//                 keeps per-(row,chunk,hi,residue) TOP-2 {m1,m2} -> 2 planes
//  3) knn_select: per row: T0 = (k+1)-th largest over all {m1,m2} (4096
//                 values).  Subsets with m2 < T0 contribute only their
//                 stored top-2 (deeper dots < T0 <= v11 -> not top-11), so
//                 if NO subset has m2 >= T0 (~97% of rows, 11 dots in 2048
//                 subsets rarely collide) the answer IS T0 — zero gather.
//                 Else: rescan only flagged subsets (~1 x 25 refs).
//
// Exactness: S = {m1,m2 per subset} ⊆ dots -> (k+1)th(S) = T0 <= v11.
// Non-flagged subsets' 3rd+ dots <= m2 < T0 <= v11 -> excluded safely.
// U = (S of non-flagged) ∪ (recomputed dots of flagged) contains every dot
// >= v11 and only dots -> (k+1)th(U) = v11.  Recomputed dots differ from
// MFMA values by ~2e-5 (same exact bf16 products, different f32 sum order)
// — far below the 2.39e-2 tolerance.  Ties at T0 are flagged (>=).
// Tie overflow (> NEXP flagged) falls back to an exact full-row scan.

#define D_DIM 128
#define TQB 256        // queries per block (8 waves x 32 rows)
#define BR 64          // refs per block iteration (r10 known-good)
#define NCH 64         // ref chunks; grid 8*64=512 blocks; 512%8==0
#define NSUB (NCH * 32) // subsets per row = 2048  (chunk x hi x residue)
#define KK 11          // selection slots (k=10 -> 11th largest)
#define NEXP 16        // expansion-subset capacity (typically 0-1 used)
#define SLOTS 25       // max refs per subset: ceil(782/32) = 25
#define DNF 2816       // LDS dot buffer: max(NEXP*SLOTS=400, 256*KK=2816)

typedef __bf16 bf16_t;
typedef bf16_t bf16x8 __attribute__((ext_vector_type(8)));
typedef float f32x16 __attribute__((ext_vector_type(16)));

__device__ __forceinline__ unsigned short f2bf(float f) {
    unsigned u = __float_as_uint(f);
    return (unsigned short)((u + 0x7fffu + ((u >> 16) & 1u)) >> 16);  // RNE
}

__global__ __launch_bounds__(256) void normalize_bf16(
    const float* __restrict__ z, const float* __restrict__ ref,
    unsigned short* __restrict__ zb, unsigned short* __restrict__ rb,
    int N, int M)
{
    const int w = threadIdx.x >> 6;
    const int l = threadIdx.x & 63;
    const int row = blockIdx.x * 4 + w;
    if (row >= N + M) return;
    const float* in; unsigned short* out; int r;
    if (row < N) { in = z;   out = zb; r = row; }
    else         { in = ref; out = rb; r = row - N; }
    const float2 v = ((const float2*)in)[(size_t)r * 64 + l];
    float ss = v.x * v.x + v.y * v.y;
    #pragma unroll
    for (int off = 32; off > 0; off >>= 1) ss += __shfl_xor(ss, off);
    const float inv = rsqrtf(ss);
    ushort2 o; o.x = f2bf(v.x * inv); o.y = f2bf(v.y * inv);
    ((ushort2*)out)[(size_t)r * 64 + l] = o;
}

// async global->LDS, 16B per lane; LDS dest is wave-uniform base + lane*16.
__device__ __forceinline__ void gld_lds16(const unsigned short* g,
                                          unsigned short* l) {
    __builtin_amdgcn_global_load_lds(
        (__attribute__((address_space(1))) void*)g,
        (__attribute__((address_space(3))) void*)l, 16, 0, 0);
}

// branchless top-2 update (order matters: m2 uses OLD m1)
#define TOP2(m1v, m2v, vv) do { float _v = (vv);                  \
        (m2v) = fmaxf((m2v), fminf((m1v), _v));                   \
        (m1v) = fmaxf((m1v), _v); } while (0)

// Single MFMA pass: per-subset TOP-2 (r10 body + top-2 epilogue).
__global__ __launch_bounds__(512) void knn_maxes(
    const unsigned short* __restrict__ zb, const unsigned short* __restrict__ rb,
    float* __restrict__ maxes, int N, int M, int chunk)
{
    __shared__ __align__(16) unsigned short Bt[2 * BR * D_DIM];

    // T1 XCD swizzle: XCD k owns ref-chunks [8k,8k+8) exclusively (1.6MB,
    // L2-fit); all 8 q-blocks of a chunk land on the same XCD.
    const int nwg = 8 * NCH;                              // 512, %8 == 0
    const int bid = (int)blockIdx.x + 8 * (int)blockIdx.y;
    const int swz = (bid & 7) * (nwg >> 3) + (bid >> 3);
    const int bx = swz & 7;
    const int by = swz >> 3;

    const int t = threadIdx.x;
    const int lane = t & 63;
    const int w = t >> 6;
    const int quad = lane >> 4;
    const int ln = lane & 15;
    const int l31 = lane & 31;
    const int hi = lane >> 5;
    const int row = bx * TQB + w * 32 + l31;   // this lane's q-row
    const int c0 = by * chunk;
    const int c1 = min(c0 + chunk, M);
    const int clen = c1 - c0;
    const int nt = (clen + BR - 1) / BR;

    // Q fragments (B operand), loop-invariant, from L2-resident zb.
    bf16x8 qfr[8];
    #pragma unroll
    for (int ks = 0; ks < 8; ++ks)
        qfr[ks] = *(const bf16x8*)&zb[(size_t)row * D_DIM + ks * 16 + hi * 8];

    float m1[16], m2[16];
    #pragma unroll
    for (int r = 0; r < 16; ++r) { m1[r] = -3.0f; m2[r] = -3.0f; }

    auto stage = [&](int half, int tile) {
        const int s0 = c0 + tile * BR;
        #pragma unroll
        for (int i = 0; i < 2; ++i) {
            const int r = w * 8 + i * 4 + quad;
            int g = s0 + r; if (g > M - 1) g = M - 1;
            const int sl = ln ^ (r & 15);               // inverse-swizzled slot
            gld_lds16(&rb[(size_t)g * D_DIM + sl * 8],
                      &Bt[half * (BR * D_DIM) + (w * 8 + i * 4) * D_DIM]);
        }
    };

    stage(0, 0);
    stage(1, nt > 1 ? 1 : 0);

    for (int it = 0; it < nt; ++it) {
        if (it + 1 < nt) asm volatile("s_waitcnt vmcnt(2)" ::: "memory");
        else             asm volatile("s_waitcnt vmcnt(0)" ::: "memory");
        __builtin_amdgcn_s_barrier();
        asm volatile("" ::: "memory");
        __builtin_amdgcn_sched_barrier(0);

        const int cur = it & 1;
        const unsigned short* Bc = &Bt[cur * (BR * D_DIM)];

        f32x16 acc0 = {0,0,0,0,0,0,0,0,0,0,0,0,0,0,0,0};
        f32x16 acc1 = {0,0,0,0,0,0,0,0,0,0,0,0,0,0,0,0};

        __builtin_amdgcn_s_setprio(1);
        #pragma unroll
        for (int ks = 0; ks < 8; ++ks) {
            const int sl = ((ks * 2 + hi) ^ ln) * 8;    // swizzled 16B slot
            bf16x8 a0 = *(const bf16x8*)&Bc[(l31)      * D_DIM + sl];
            bf16x8 a1 = *(const bf16x8*)&Bc[(32 + l31) * D_DIM + sl];
            acc0 = __builtin_amdgcn_mfma_f32_32x32x16_bf16(a0, qfr[ks], acc0, 0, 0, 0);
            acc1 = __builtin_amdgcn_mfma_f32_32x32x16_bf16(a1, qfr[ks], acc1, 0, 0, 0);
        }
        __builtin_amdgcn_s_setprio(0);

        // acc0/acc1 reg r = dot(q=row, ref = c0+it*64+{0,32}+crow),
        // crow = (r&3)+8*(r>>2)+4*hi  [m74/m101 verified layout].
        const int rem = clen - it * BR;
        if (rem >= BR) {
            #pragma unroll
            for (int r = 0; r < 16; ++r) {
                TOP2(m1[r], m2[r], acc0[r]);
                TOP2(m1[r], m2[r], acc1[r]);
            }
        } else {
            #pragma unroll
            for (int r = 0; r < 16; ++r) {
                const int crow = (r & 3) + 8 * (r >> 2) + 4 * hi;
                if (crow < rem)      { TOP2(m1[r], m2[r], acc0[r]); }
                if (32 + crow < rem) { TOP2(m1[r], m2[r], acc1[r]); }
            }
        }

        __builtin_amdgcn_sched_barrier(0);
        asm volatile("" ::: "memory");
        __builtin_amdgcn_s_barrier();
        if (it + 2 < nt) stage(cur, it + 2);
    }

    // Two planes: m1 at [row][s], m2 at [N*NSUB + row*NSUB + s];
    // subset s = by*32 + hi*16 + r.
    float* mp1 = &maxes[(size_t)row * NSUB + by * 32 + hi * 16];
    float* mp2 = mp1 + (size_t)N * NSUB;
    #pragma unroll
    for (int r4 = 0; r4 < 4; ++r4) {
        float4 v1 = { m1[r4*4], m1[r4*4+1], m1[r4*4+2], m1[r4*4+3] };
        float4 v2 = { m2[r4*4], m2[r4*4+1], m2[r4*4+2], m2[r4*4+3] };
        *(float4*)&mp1[r4 * 4] = v1;
        *(float4*)&mp2[r4 * 4] = v2;
    }
}

// Per-lane sorted top-(KK) slots, then kk+1 global max-extractions with
// static-shift pop (rule #20: no dynamic register indexing).
__device__ __forceinline__ float kth_largest_64(float* s, int kk, int lane) {
    float cur = -3.0f;
    for (int it = 0; it <= kk; ++it) {
        float m = s[0];
        #pragma unroll
        for (int off = 32; off > 0; off >>= 1) m = fmaxf(m, __shfl_xor(m, off));
        cur = m;
        unsigned long long b = __ballot(s[0] == m);
        bool owner = ((int)(__ffsll(b) - 1) == lane);
        #pragma unroll
        for (int j = 0; j < KK - 1; ++j) s[j] = owner ? s[j + 1] : s[j];
        if (owner) s[KK - 1] = -3.0f;
    }
    return cur;
}

// Wave-level: extract the wave's top-(kk+1) values to LDS (descending).
__device__ __forceinline__ void wave_topk_to_lds(float* s, int kk, int lane,
                                                 float* dst) {
    for (int it = 0; it <= kk; ++it) {
        float m = s[0];
        #pragma unroll
        for (int off = 32; off > 0; off >>= 1) m = fmaxf(m, __shfl_xor(m, off));
        if (lane == 0) dst[it] = m;
        unsigned long long b = __ballot(s[0] == m);
        bool owner = ((int)(__ffsll(b) - 1) == lane);
        #pragma unroll
        for (int j = 0; j < KK - 1; ++j) s[j] = owner ? s[j + 1] : s[j];
        if (owner) s[KK - 1] = -3.0f;
    }
}

__device__ __forceinline__ void sorted_insert(float* s, float v) {
    #pragma unroll
    for (int j = 0; j < KK; ++j) {
        float hi = fmaxf(s[j], v), lo = fminf(s[j], v);
        s[j] = hi; v = lo;
    }
}

// Per-row select over the top-2 planes; gather only for flagged subsets.
__global__ __launch_bounds__(256) void knn_select(
    const unsigned short* __restrict__ zb, const unsigned short* __restrict__ rb,
    const float* __restrict__ maxes, const int* __restrict__ kp,
    float* __restrict__ out, int N, int M, int chunk)
{
    const int row = blockIdx.x;
    const int t = threadIdx.x;
    const int lane = t & 63;
    const int wv = t >> 6;                        // wave 0..3
    __shared__ float dbuf[DNF];
    __shared__ float tops[4 * KK];
    __shared__ float T_s;
    __shared__ int expl[NEXP];
    __shared__ int ecnt;

    const int kk = *kp;   // 10
    if (t == 0) ecnt = 0;

    const float* m1p = maxes + (size_t)row * NSUB;
    const float* m2p = m1p + (size_t)N * NSUB;

    // Phase 1 (all 4 waves): per-wave top-(kk+1) over its 512 subsets' m1,m2.
    {
        float s[KK];
        #pragma unroll
        for (int j = 0; j < KK; ++j) s[j] = -3.0f;
        #pragma unroll
        for (int i = 0; i < NSUB / 256; ++i) {    // 8+8 coalesced loads/lane
            sorted_insert(s, m1p[wv * (NSUB / 4) + lane + 64 * i]);
            sorted_insert(s, m2p[wv * (NSUB / 4) + lane + 64 * i]);
        }
        wave_topk_to_lds(s, kk, lane, &tops[wv * KK]);
    }
    __syncthreads();

    // Phase 2 (wave 0): merge 4x(kk+1) wave-tops -> T0 = (kk+1)-th of S.
    if (t < 64) {
        float s[KK];
        s[0] = (t < 4 * (kk + 1)) ? tops[t] : -3.0f;
        #pragma unroll
        for (int j = 1; j < KK; ++j) s[j] = -3.0f;
        const float T = kth_largest_64(s, kk, lane);
        if (t == 0) T_s = T;
    }
    __syncthreads();
    const float T0 = T_s;

    // Phase 3: flag subsets whose m2 >= T0 (need expansion).
    #pragma unroll
    for (int i = 0; i < NSUB / 256; ++i) {
        int idx = wv * (NSUB / 4) + lane + 64 * i;
        if (m2p[idx] >= T0) {
            int e = atomicAdd(&ecnt, 1);
            if (e < NEXP) expl[e] = idx;
        }
    }
    __syncthreads();
    const int en = ecnt;

    if (en == 0) {   // common (~97% of rows): answer is T0 itself
        if (t == 0) out[row] = sqrtf(fmaxf(2.0f - 2.0f * T0, 1e-12f));
        return;
    }

    // Rare path: recompute flagged subsets' dots; rebuild the selection.
    const int gl = t & 7;
    const int grp = t >> 3;                       // 0..31 groups
    float q0r[8], q1r[8];
    {
        bf16x8 qv0 = *(const bf16x8*)&zb[(size_t)row * D_DIM + gl * 8];
        bf16x8 qv1 = *(const bf16x8*)&zb[(size_t)row * D_DIM + 64 + gl * 8];
        #pragma unroll
        for (int e = 0; e < 8; ++e) { q0r[e] = (float)qv0[e]; q1r[e] = (float)qv1[e]; }
    }

    const int slots = (chunk + 31) >> 5;          // ceil(782/32) = 25
    int nsel;

    if (en <= NEXP && slots <= SLOTS) {
        const int W = en * slots;                 // <= 400 live slots
        int ci = grp / slots;
        int sl = grp - ci * slots;
        for (int gs = grp; gs < W; gs += 32) {
            const int s  = expl[ci];
            const int by = s >> 5;
            const int h2 = (s >> 4) & 1;
            const int r  = s & 15;
            const int base = (r & 3) + 8 * (r >> 2) + 4 * h2;
            const int c0 = by * chunk;
            const int c1 = min(c0 + chunk, M);
            const int ref = c0 + sl * 32 + base;
            const bool valid = ref < c1;
            float p = 0.f;
            if (valid) {
                const unsigned short* rp = &rb[(size_t)ref * D_DIM + gl * 8];
                bf16x8 r0 = *(const bf16x8*)rp;          // coalesced 128B
                bf16x8 r1 = *(const bf16x8*)(rp + 64);   // per 8-lane group
                #pragma unroll
                for (int e = 0; e < 8; ++e) {
                    p = fmaf((float)r0[e], q0r[e], p);
                    p = fmaf((float)r1[e], q1r[e], p);
                }
            }
            p += __shfl_xor(p, 1);
            p += __shfl_xor(p, 2);
            p += __shfl_xor(p, 4);
            if (gl == 0) dbuf[gs] = valid ? p : -3.0f;
            sl += 32;
            while (sl >= slots) { sl -= slots; ++ci; }
        }
        __syncthreads();

        // Rebuild per-wave tops EXCLUDING flagged subsets' stored values.
        {
            float s[KK];
            #pragma unroll
            for (int j = 0; j < KK; ++j) s[j] = -3.0f;
            #pragma unroll
            for (int i = 0; i < NSUB / 256; ++i) {
                int idx = wv * (NSUB / 4) + lane + 64 * i;
                bool skip = false;
                for (int j = 0; j < en && j < NEXP; ++j) skip |= (idx == expl[j]);
                sorted_insert(s, skip ? -3.0f : m1p[idx]);
                sorted_insert(s, skip ? -3.0f : m2p[idx]);
            }
            wave_topk_to_lds(s, kk, lane, &tops[wv * KK]);
        }
        nsel = W;
        __syncthreads();

        if (t < 64) {
            float s[KK];
            s[0] = (t < 4 * (kk + 1)) ? tops[t] : -3.0f;
            #pragma unroll
            for (int j = 1; j < KK; ++j) s[j] = -3.0f;
            for (int j = t; j < nsel; j += 64) sorted_insert(s, dbuf[j]);
            const float cur = kth_largest_64(s, kk, lane);
            if (t == 0) out[row] = sqrtf(fmaxf(2.0f - 2.0f * cur, 1e-12f));
        }
        return;
    }

    // Overflow fallback (~never): exact full scan of this row.
    {
        float s[KK];
        #pragma unroll
        for (int j = 0; j < KK; ++j) s[j] = -3.0f;
        for (int g = grp; g < M; g += 32) {
            const unsigned short* rp = &rb[(size_t)g * D_DIM + gl * 8];
            bf16x8 r0 = *(const bf16x8*)rp;
            bf16x8 r1 = *(const bf16x8*)(rp + 64);
            float p = 0.f;
            #pragma unroll
            for (int e = 0; e < 8; ++e) {
                p = fmaf((float)r0[e], q0r[e], p);
                p = fmaf((float)r1[e], q1r[e], p);
            }
            p += __shfl_xor(p, 1);
            p += __shfl_xor(p, 2);
            p += __shfl_xor(p, 4);
            sorted_insert(s, p);
        }
        #pragma unroll
        for (int j = 0; j < KK; ++j) dbuf[t * KK + j] = s[j];   // 256*11 = DNF
    }
    __syncthreads();
    if (t < 64) {
        float s[KK];
        #pragma unroll
        for (int j = 0; j < KK; ++j) s[j] = -3.0f;
        for (int j = t; j < DNF; j += 64) sorted_insert(s, dbuf[j]);
        const float cur = kth_largest_64(s, kk, lane);
        if (t == 0) out[row] = sqrtf(fmaxf(2.0f - 2.0f * cur, 1e-12f));
    }
}

extern "C" void kernel_launch(void* const* d_in, const int* in_sizes, int n_in,
                              void* d_out, int out_size, void* d_ws, size_t ws_size,
                              hipStream_t stream) {
    const float* z   = (const float*)d_in[0];
    const float* ref = (const float*)d_in[1];
    const int*   kp  = (const int*)d_in[2];
    float* out = (float*)d_out;

    const int N = in_sizes[0] / D_DIM;   // 2048
    const int M = in_sizes[1] / D_DIM;   // 50000

    unsigned short* zbuf = (unsigned short*)d_ws;             // N*128 bf16
    unsigned short* rbuf = zbuf + (size_t)N * D_DIM;          // M*128 bf16
    float* maxes = (float*)(rbuf + (size_t)M * D_DIM);        // 2 planes x N*NSUB (32MB)

    normalize_bf16<<<(N + M + 3) / 4, 256, 0, stream>>>(z, ref, zbuf, rbuf, N, M);

    const int chunk = (M + NCH - 1) / NCH;    // 782
    dim3 grid(N / TQB, NCH);                  // 8 x 64 = 512 blocks

    knn_maxes<<<grid, 512, 0, stream>>>(zbuf, rbuf, maxes, N, M, chunk);
    knn_select<<<N, 256, 0, stream>>>(zbuf, rbuf, maxes, kp, out, N, M, chunk);
}

// Round 14
// 147.915 us; speedup vs baseline: 1.0715x; 1.0715x over previous
//
#include <hip/hip_runtime.h>

// KNN k-th smallest distance — single MFMA pass + fused candidate select.
// dist = sqrt(2 - 2*dot(zn,rn)); sorted(dist)[k] == (k+1)-th LARGEST dot.
//  1) normalize_bf16: fused z+ref rows -> L2-normalized bf16
//  2) knn_maxes:  MFMA dots (r10 known-good 8-wave/256q body).  Epilogue
//                 = HALF-SPLIT subset max: mxA from acc0, mxB from acc1 —
//                 SAME 32 fmax/iter as r10 (r13 lesson: epilogue tolerates
//                 zero extra ops).  4096 subsets/row, 13 refs each.
//                 Stored as bf16 (RNE is monotone -> order stats preserved).
//  3) knn_select: per row: T = (k+1)-th largest of 4096 bf16 subset maxes
//                 (parallel across 4 waves) -> candidates {m >= T} (~11-15)
//                 -> cooperative 8-lane coalesced gather of candidate refs
//                 (13/subset, HALF of r10's 25) -> (k+1)-th largest -> dist.
//
// Exactness: T0 computed from rounded maxes; RNE monotone => sorted(r(x)) =
// r(sorted(x)) => T0 = r(T_true).  A subset holding a top-11 dot has
// m1 >= v11 >= T_true => r(m1) >= r(T_true) = T0 => flagged.  Gathered dots
// therefore contain ALL top-11 dots; (k+1)-th largest of gathered == v11.
// Recomputed dots sum the identical exact bf16 products in f32 (different
// order) -> ordering noise ~2e-5, far below the 2.39e-2 tolerance.
// Subsets (chunk by, half, hi, residue) PARTITION each row's refs; tails
// masked identically (crow<rem in maxes, ref<c1 in select).  Rounding ties
// only ENLARGE the candidate set; overflow (cn > NCAND) falls back to an
// exact full-row scan.

#define D_DIM 128
#define TQB 256        // queries per block (8 waves x 32 rows)
#define BR 64          // refs per block iteration (r10 known-good)
#define NCH 64         // ref chunks; grid 8*64=512 blocks; 512%8==0
#define NSUB (NCH * 64) // subsets per row = 4096  (chunk x half x hi x residue)
#define KK 11          // selection slots (k=10 -> 11th largest)
#define NCAND 32       // candidate-subset capacity (11 + rounding ties)
#define SLOTS 13       // max refs per subset: ceil(782/64) = 13
#define DNF 2816       // LDS dot buffer: max(NCAND*SLOTS=416, 256*KK=2816)

typedef __bf16 bf16_t;
typedef bf16_t bf16x8 __attribute__((ext_vector_type(8)));
typedef float f32x16 __attribute__((ext_vector_type(16)));

__device__ __forceinline__ unsigned short f2bf(float f) {
    unsigned u = __float_as_uint(f);
    return (unsigned short)((u + 0x7fffu + ((u >> 16) & 1u)) >> 16);  // RNE
}
__device__ __forceinline__ float bf2f(unsigned short u) {
    return __uint_as_float((unsigned)u << 16);
}

__global__ __launch_bounds__(256) void normalize_bf16(
    const float* __restrict__ z, const float* __restrict__ ref,
    unsigned short* __restrict__ zb, unsigned short* __restrict__ rb,
    int N, int M)
{
    const int w = threadIdx.x >> 6;
    const int l = threadIdx.x & 63;
    const int row = blockIdx.x * 4 + w;
    if (row >= N + M) return;
    const float* in; unsigned short* out; int r;
    if (row < N) { in = z;   out = zb; r = row; }
    else         { in = ref; out = rb; r = row - N; }
    const float2 v = ((const float2*)in)[(size_t)r * 64 + l];
    float ss = v.x * v.x + v.y * v.y;
    #pragma unroll
    for (int off = 32; off > 0; off >>= 1) ss += __shfl_xor(ss, off);
    const float inv = rsqrtf(ss);
    ushort2 o; o.x = f2bf(v.x * inv); o.y = f2bf(v.y * inv);
    ((ushort2*)out)[(size_t)r * 64 + l] = o;
}

// async global->LDS, 16B per lane; LDS dest is wave-uniform base + lane*16.
__device__ __forceinline__ void gld_lds16(const unsigned short* g,
                                          unsigned short* l) {
    __builtin_amdgcn_global_load_lds(
        (__attribute__((address_space(1))) void*)g,
        (__attribute__((address_space(3))) void*)l, 16, 0, 0);
}

// Single MFMA pass: half-split subset maxes, bf16-stored.
__global__ __launch_bounds__(512) void knn_maxes(
    const unsigned short* __restrict__ zb, const unsigned short* __restrict__ rb,
    unsigned short* __restrict__ maxes, int N, int M, int chunk)
{
    __shared__ __align__(16) unsigned short Bt[2 * BR * D_DIM];

    // T1 XCD swizzle: XCD k owns ref-chunks [8k,8k+8) exclusively (1.6MB,
    // L2-fit); all 8 q-blocks of a chunk land on the same XCD.
    const int nwg = 8 * NCH;                              // 512, %8 == 0
    const int bid = (int)blockIdx.x + 8 * (int)blockIdx.y;
    const int swz = (bid & 7) * (nwg >> 3) + (bid >> 3);
    const int bx = swz & 7;
    const int by = swz >> 3;

    const int t = threadIdx.x;
    const int lane = t & 63;
    const int w = t >> 6;
    const int quad = lane >> 4;
    const int ln = lane & 15;
    const int l31 = lane & 31;
    const int hi = lane >> 5;
    const int row = bx * TQB + w * 32 + l31;   // this lane's q-row
    const int c0 = by * chunk;
    const int c1 = min(c0 + chunk, M);
    const int clen = c1 - c0;
    const int nt = (clen + BR - 1) / BR;

    // Q fragments (B operand), loop-invariant, from L2-resident zb.
    bf16x8 qfr[8];
    #pragma unroll
    for (int ks = 0; ks < 8; ++ks)
        qfr[ks] = *(const bf16x8*)&zb[(size_t)row * D_DIM + ks * 16 + hi * 8];

    float mxA[16], mxB[16];    // half-split: A <- acc0 (refs+0), B <- acc1 (+32)
    #pragma unroll
    for (int r = 0; r < 16; ++r) { mxA[r] = -3.0f; mxB[r] = -3.0f; }

    auto stage = [&](int half, int tile) {
        const int s0 = c0 + tile * BR;
        #pragma unroll
        for (int i = 0; i < 2; ++i) {
            const int r = w * 8 + i * 4 + quad;
            int g = s0 + r; if (g > M - 1) g = M - 1;
            const int sl = ln ^ (r & 15);               // inverse-swizzled slot
            gld_lds16(&rb[(size_t)g * D_DIM + sl * 8],
                      &Bt[half * (BR * D_DIM) + (w * 8 + i * 4) * D_DIM]);
        }
    };

    stage(0, 0);
    stage(1, nt > 1 ? 1 : 0);

    for (int it = 0; it < nt; ++it) {
        if (it + 1 < nt) asm volatile("s_waitcnt vmcnt(2)" ::: "memory");
        else             asm volatile("s_waitcnt vmcnt(0)" ::: "memory");
        __builtin_amdgcn_s_barrier();
        asm volatile("" ::: "memory");
        __builtin_amdgcn_sched_barrier(0);

        const int cur = it & 1;
        const unsigned short* Bc = &Bt[cur * (BR * D_DIM)];

        f32x16 acc0 = {0,0,0,0,0,0,0,0,0,0,0,0,0,0,0,0};
        f32x16 acc1 = {0,0,0,0,0,0,0,0,0,0,0,0,0,0,0,0};

        __builtin_amdgcn_s_setprio(1);
        #pragma unroll
        for (int ks = 0; ks < 8; ++ks) {
            const int sl = ((ks * 2 + hi) ^ ln) * 8;    // swizzled 16B slot
            bf16x8 a0 = *(const bf16x8*)&Bc[(l31)      * D_DIM + sl];
            bf16x8 a1 = *(const bf16x8*)&Bc[(32 + l31) * D_DIM + sl];
            acc0 = __builtin_amdgcn_mfma_f32_32x32x16_bf16(a0, qfr[ks], acc0, 0, 0, 0);
            acc1 = __builtin_amdgcn_mfma_f32_32x32x16_bf16(a1, qfr[ks], acc1, 0, 0, 0);
        }
        __builtin_amdgcn_s_setprio(0);

        // acc0/acc1 reg r = dot(q=row, ref = c0+it*64+{0,32}+crow),
        // crow = (r&3)+8*(r>>2)+4*hi  [m74/m101 verified layout].
        // Half-split epilogue: SAME 32 fmax/iter as r10, no dep chains.
        const int rem = clen - it * BR;
        if (rem >= BR) {
            #pragma unroll
            for (int r = 0; r < 16; ++r) {
                mxA[r] = fmaxf(mxA[r], acc0[r]);
                mxB[r] = fmaxf(mxB[r], acc1[r]);
            }
        } else {
            #pragma unroll
            for (int r = 0; r < 16; ++r) {
                const int crow = (r & 3) + 8 * (r >> 2) + 4 * hi;
                if (crow < rem)      mxA[r] = fmaxf(mxA[r], acc0[r]);
                if (32 + crow < rem) mxB[r] = fmaxf(mxB[r], acc1[r]);
            }
        }

        __builtin_amdgcn_sched_barrier(0);
        asm volatile("" ::: "memory");
        __builtin_amdgcn_s_barrier();
        if (it + 2 < nt) stage(cur, it + 2);
    }

    // bf16 write: subset s = by*64 + half*32 + hi*16 + r.
    union { unsigned short u[16]; uint4 q[2]; } h0, h1;
    #pragma unroll
    for (int r = 0; r < 16; ++r) { h0.u[r] = f2bf(mxA[r]); h1.u[r] = f2bf(mxB[r]); }
    unsigned short* mp = &maxes[(size_t)row * NSUB + by * 64 + hi * 16];
    *(uint4*)&mp[0]      = h0.q[0];
    *(uint4*)&mp[8]      = h0.q[1];
    *(uint4*)&mp[32]     = h1.q[0];
    *(uint4*)&mp[40]     = h1.q[1];
}

// Per-lane sorted top-(KK) slots, then kk+1 global max-extractions with
// static-shift pop (rule #20: no dynamic register indexing).
__device__ __forceinline__ float kth_largest_64(float* s, int kk, int lane) {
    float cur = -3.0f;
    for (int it = 0; it <= kk; ++it) {
        float m = s[0];
        #pragma unroll
        for (int off = 32; off > 0; off >>= 1) m = fmaxf(m, __shfl_xor(m, off));
        cur = m;
        unsigned long long b = __ballot(s[0] == m);
        bool owner = ((int)(__ffsll(b) - 1) == lane);
        #pragma unroll
        for (int j = 0; j < KK - 1; ++j) s[j] = owner ? s[j + 1] : s[j];
        if (owner) s[KK - 1] = -3.0f;
    }
    return cur;
}

// Wave-level: extract the wave's top-(kk+1) values to LDS (descending).
__device__ __forceinline__ void wave_topk_to_lds(float* s, int kk, int lane,
                                                 float* dst) {
    for (int it = 0; it <= kk; ++it) {
        float m = s[0];
        #pragma unroll
        for (int off = 32; off > 0; off >>= 1) m = fmaxf(m, __shfl_xor(m, off));
        if (lane == 0) dst[it] = m;
        unsigned long long b = __ballot(s[0] == m);
        bool owner = ((int)(__ffsll(b) - 1) == lane);
        #pragma unroll
        for (int j = 0; j < KK - 1; ++j) s[j] = owner ? s[j + 1] : s[j];
        if (owner) s[KK - 1] = -3.0f;
    }
}

__device__ __forceinline__ void sorted_insert(float* s, float v) {
    #pragma unroll
    for (int j = 0; j < KK; ++j) {
        float hi = fmaxf(s[j], v), lo = fminf(s[j], v);
        s[j] = hi; v = lo;
    }
}

// Fused per-row select: threshold + candidate gather + exact (k+1)-th.
__global__ __launch_bounds__(256) void knn_select(
    const unsigned short* __restrict__ zb, const unsigned short* __restrict__ rb,
    const unsigned short* __restrict__ maxes, const int* __restrict__ kp,
    float* __restrict__ out, int M, int chunk)
{
    const int row = blockIdx.x;
    const int t = threadIdx.x;
    const int lane = t & 63;
    const int wv = t >> 6;                        // wave 0..3
    __shared__ float dbuf[DNF];
    __shared__ float tops[4 * KK];
    __shared__ float T_s;
    __shared__ int cand_s[NCAND];
    __shared__ int cn_s;

    const int kk = *kp;   // 10
    if (t == 0) cn_s = 0;

    const unsigned short* m1p = maxes + (size_t)row * NSUB;

    // Phase A1 (all 4 waves): per-wave top-(kk+1) over its 1024 subsets.
    {
        float s[KK];
        #pragma unroll
        for (int j = 0; j < KK; ++j) s[j] = -3.0f;
        #pragma unroll
        for (int i = 0; i < NSUB / 256; ++i)      // 16 coalesced loads/lane
            sorted_insert(s, bf2f(m1p[wv * (NSUB / 4) + lane + 64 * i]));
        wave_topk_to_lds(s, kk, lane, &tops[wv * KK]);
    }

    // q slice into regs (independent; overlaps phase A).  Lane gl covers
    // elements [gl*8, gl*8+8) and [64+gl*8, ...): 8-lane group covers 128.
    const int gl = t & 7;
    const int grp = t >> 3;                       // 0..31 groups per block
    float q0r[8], q1r[8];
    {
        bf16x8 qv0 = *(const bf16x8*)&zb[(size_t)row * D_DIM + gl * 8];
        bf16x8 qv1 = *(const bf16x8*)&zb[(size_t)row * D_DIM + 64 + gl * 8];
        #pragma unroll
        for (int e = 0; e < 8; ++e) { q0r[e] = (float)qv0[e]; q1r[e] = (float)qv1[e]; }
    }
    __syncthreads();

    // Phase A2 (wave 0): merge 4x(kk+1) wave-tops -> global (kk+1)-th = T.
    if (t < 64) {
        float s[KK];
        s[0] = (t < 4 * (kk + 1)) ? tops[t] : -3.0f;
        #pragma unroll
        for (int j = 1; j < KK; ++j) s[j] = -3.0f;
        const float T = kth_largest_64(s, kk, lane);
        if (t == 0) T_s = T;
    }
    __syncthreads();

    // Phase A3 (all waves): append candidate subsets (max >= T).
    {
        const float T = T_s;
        #pragma unroll
        for (int i = 0; i < NSUB / 256; ++i) {    // reload (cache-hot)
            int idx = wv * (NSUB / 4) + lane + 64 * i;
            if (bf2f(m1p[idx]) >= T) {
                int sl = atomicAdd(&cn_s, 1);
                if (sl < NCAND) cand_s[sl] = idx;
            }
        }
    }
    __syncthreads();

    const int cn = cn_s;
    const int slots = (chunk + BR - 1) / BR;      // ceil(782/64) = 13
    int nsel;

    if (cn <= NCAND && slots <= SLOTS) {
        // Flattened gather: independent (ci, sl) work items -> loads pipeline.
        // Subset s: refs { c0 + j*64 + half*32 + crow : j in [0,slots) } ∩ [c0,c1).
        const int W = cn * slots;                 // <= 416 live slots
        int ci = grp / slots;                     // one div; then incremental
        int sl = grp - ci * slots;
        for (int gs = grp; gs < W; gs += 32) {
            const int s    = cand_s[ci];
            const int by   = s >> 6;
            const int half = (s >> 5) & 1;
            const int h2   = (s >> 4) & 1;
            const int r    = s & 15;
            const int off  = half * 32 + (r & 3) + 8 * (r >> 2) + 4 * h2;
            const int c0 = by * chunk;
            const int c1 = min(c0 + chunk, M);
            const int ref = c0 + sl * 64 + off;
            const bool valid = ref < c1;
            float p = 0.f;
            if (valid) {
                const unsigned short* rp = &rb[(size_t)ref * D_DIM + gl * 8];
                bf16x8 r0 = *(const bf16x8*)rp;          // coalesced 128B
                bf16x8 r1 = *(const bf16x8*)(rp + 64);   // per 8-lane group
                #pragma unroll
                for (int e = 0; e < 8; ++e) {
                    p = fmaf((float)r0[e], q0r[e], p);
                    p = fmaf((float)r1[e], q1r[e], p);
                }
            }
            p += __shfl_xor(p, 1);                // butterfly within group
            p += __shfl_xor(p, 2);
            p += __shfl_xor(p, 4);
            if (gl == 0) dbuf[gs] = valid ? p : -3.0f;   // each slot once
            sl += 32;
            while (sl >= slots) { sl -= slots; ++ci; }
        }
        nsel = W;
    } else {
        // Tie-overflow fallback (rare): exact full scan of this row.
        float s[KK];
        #pragma unroll
        for (int j = 0; j < KK; ++j) s[j] = -3.0f;
        for (int g = grp; g < M; g += 32) {
            const unsigned short* rp = &rb[(size_t)g * D_DIM + gl * 8];
            bf16x8 r0 = *(const bf16x8*)rp;
            bf16x8 r1 = *(const bf16x8*)(rp + 64);
            float p = 0.f;
            #pragma unroll
            for (int e = 0; e < 8; ++e) {
                p = fmaf((float)r0[e], q0r[e], p);
                p = fmaf((float)r1[e], q1r[e], p);
            }
            p += __shfl_xor(p, 1);
            p += __shfl_xor(p, 2);
            p += __shfl_xor(p, 4);
            sorted_insert(s, p);
        }
        #pragma unroll
        for (int j = 0; j < KK; ++j) dbuf[t * KK + j] = s[j];   // 256*11 = DNF
        nsel = DNF;
    }
    __syncthreads();

    // Final: (kk+1)-th largest over the live dbuf range (wave 0).
    if (t < 64) {
        float s[KK];
        #pragma unroll
        for (int j = 0; j < KK; ++j) s[j] = -3.0f;
        for (int j = t; j < nsel; j += 64) sorted_insert(s, dbuf[j]);
        const float cur = kth_largest_64(s, kk, lane);
        if (t == 0) out[row] = sqrtf(fmaxf(2.0f - 2.0f * cur, 1e-12f));
    }
}

extern "C" void kernel_launch(void* const* d_in, const int* in_sizes, int n_in,
                              void* d_out, int out_size, void* d_ws, size_t ws_size,
                              hipStream_t stream) {
    const float* z   = (const float*)d_in[0];
    const float* ref = (const float*)d_in[1];
    const int*   kp  = (const int*)d_in[2];
    float* out = (float*)d_out;

    const int N = in_sizes[0] / D_DIM;   // 2048
    const int M = in_sizes[1] / D_DIM;   // 50000

    unsigned short* zbuf = (unsigned short*)d_ws;             // N*128 bf16
    unsigned short* rbuf = zbuf + (size_t)N * D_DIM;          // M*128 bf16
    unsigned short* maxes = rbuf + (size_t)M * D_DIM;         // N*NSUB bf16 (16MB)

    normalize_bf16<<<(N + M + 3) / 4, 256, 0, stream>>>(z, ref, zbuf, rbuf, N, M);

    const int chunk = (M + NCH - 1) / NCH;    // 782
    dim3 grid(N / TQB, NCH);                  // 8 x 64 = 512 blocks

    knn_maxes<<<grid, 512, 0, stream>>>(zbuf, rbuf, maxes, N, M, chunk);
    knn_select<<<N, 256, 0, stream>>>(zbuf, rbuf, maxes, kp, out, M, chunk);
}

// Round 15
// 137.746 us; speedup vs baseline: 1.1506x; 1.0738x over previous
//
#include <hip/hip_runtime.h>

// KNN k-th smallest distance — single MFMA pass + fused candidate select.
// dist = sqrt(2 - 2*dot(zn,rn)); sorted(dist)[k] == (k+1)-th LARGEST dot.
//  1) normalize_bf16: fused z+ref rows -> L2-normalized bf16
//  2) knn_maxes:     MFMA dots (8-wave/256q attention shape), per-(row,
//                    chunk,hi,residue) subset MAX in-register -> maxes
//  3) knn_select:    per row (fused): T = (k+1)-th largest subset max ->
//                    candidate subsets (LDS) -> cooperative 8-lane coalesced
//                    dot recompute of ONLY candidate refs (~11 x 24) ->
//                    (k+1)-th largest -> dist.
//
// Round-15: TERMINAL REVERT to the round-10 artifact (best verified:
// 137.4us).  Four consecutive attempts to beat it were falsified:
//   r11 (BR=128 event-amortization)      146.3  [maxes 46.5, occ down]
//   r12 (parallel threshold + decode)    139.9  [neutral/noise]
//   r13 (per-subset top-2 epilogue)      158.5  [maxes 57.9: epilogue VALU]
//   r14 (half-split + bf16 maxes)        147.9  [maxes 47.2: +VGPR]
// Budget at this artifact: fill 45 (harness re-poison, untouchable) +
// maxes 44 (m233 2-phase structural plateau; 7 variants pinned) +
// normalize 7 (~90% achievable BW) + select ~25 (L3-gather latency floor;
// 3 restructures neutral) + launch gaps ~15.
//
// Exactness: candidate selection uses the SAME MFMA-produced maxes as T, so
// coverage is exact (every top-11 dot lives in a subset whose max >= T; the
// 11th largest of all candidate-subset dots == 11th largest overall).
// Recomputed dots sum the identical exact bf16 products in f32 (different
// order) -> ordering noise ~2e-5 in dot space, ~1e-4 in dist, far below the
// 2.39e-2 tolerance.  Subsets (chunk by, hi, residue r) PARTITION each
// row's refs; tails masked identically (ref < c1) in both kernels.  Tie
// overflow (cn > NCAND) falls back to an exact full scan of the row.

#define D_DIM 128
#define TQB 256        // queries per block (8 waves x 32 rows)
#define BR 64          // refs per block iteration
#define NCH 64         // ref chunks; grid 8*64=512 blocks; 512%8==0
#define NSUB (NCH * 32) // subsets per row = 2048  (chunk x hi x residue)
#define KK 11          // selection slots (k=10 -> 11th largest)
#define NCAND 32       // candidate-subset capacity per row (>=11; ties only)
#define SLOTS 26       // max slots per subset: 13 tiles x {0,32}
#define DNF 2816       // LDS dot buffer: max(NCAND*SLOTS=832, 256*KK=2816)

typedef __bf16 bf16_t;
typedef bf16_t bf16x8 __attribute__((ext_vector_type(8)));
typedef float f32x16 __attribute__((ext_vector_type(16)));

__device__ __forceinline__ unsigned short f2bf(float f) {
    unsigned u = __float_as_uint(f);
    return (unsigned short)((u + 0x7fffu + ((u >> 16) & 1u)) >> 16);  // RNE
}

__global__ __launch_bounds__(256) void normalize_bf16(
    const float* __restrict__ z, const float* __restrict__ ref,
    unsigned short* __restrict__ zb, unsigned short* __restrict__ rb,
    int N, int M)
{
    const int w = threadIdx.x >> 6;
    const int l = threadIdx.x & 63;
    const int row = blockIdx.x * 4 + w;
    if (row >= N + M) return;
    const float* in; unsigned short* out; int r;
    if (row < N) { in = z;   out = zb; r = row; }
    else         { in = ref; out = rb; r = row - N; }
    const float2 v = ((const float2*)in)[(size_t)r * 64 + l];
    float ss = v.x * v.x + v.y * v.y;
    #pragma unroll
    for (int off = 32; off > 0; off >>= 1) ss += __shfl_xor(ss, off);
    const float inv = rsqrtf(ss);
    ushort2 o; o.x = f2bf(v.x * inv); o.y = f2bf(v.y * inv);
    ((ushort2*)out)[(size_t)r * 64 + l] = o;
}

// async global->LDS, 16B per lane; LDS dest is wave-uniform base + lane*16.
__device__ __forceinline__ void gld_lds16(const unsigned short* g,
                                          unsigned short* l) {
    __builtin_amdgcn_global_load_lds(
        (__attribute__((address_space(1))) void*)g,
        (__attribute__((address_space(3))) void*)l, 16, 0, 0);
}

// Single MFMA pass: subset maxes only (r10 body, verified 44us / 137.4 total).
__global__ __launch_bounds__(512) void knn_maxes(
    const unsigned short* __restrict__ zb, const unsigned short* __restrict__ rb,
    float* __restrict__ maxes, int N, int M, int chunk)
{
    __shared__ __align__(16) unsigned short Bt[2 * BR * D_DIM];

    // T1 XCD swizzle: XCD k owns ref-chunks [8k,8k+8) exclusively (1.6MB,
    // L2-fit); all 8 q-blocks of a chunk land on the same XCD.
    const int nwg = 8 * NCH;                              // 512, %8 == 0
    const int bid = (int)blockIdx.x + 8 * (int)blockIdx.y;
    const int swz = (bid & 7) * (nwg >> 3) + (bid >> 3);
    const int bx = swz & 7;
    const int by = swz >> 3;

    const int t = threadIdx.x;
    const int lane = t & 63;
    const int w = t >> 6;
    const int quad = lane >> 4;
    const int ln = lane & 15;
    const int l31 = lane & 31;
    const int hi = lane >> 5;
    const int row = bx * TQB + w * 32 + l31;   // this lane's q-row
    const int c0 = by * chunk;
    const int c1 = min(c0 + chunk, M);
    const int clen = c1 - c0;
    const int nt = (clen + BR - 1) / BR;

    // Q fragments (B operand), loop-invariant, from L2-resident zb.
    bf16x8 qfr[8];
    #pragma unroll
    for (int ks = 0; ks < 8; ++ks)
        qfr[ks] = *(const bf16x8*)&zb[(size_t)row * D_DIM + ks * 16 + hi * 8];

    float mx[16];
    #pragma unroll
    for (int r = 0; r < 16; ++r) mx[r] = -3.0f;

    auto stage = [&](int half, int tile) {
        const int s0 = c0 + tile * BR;
        #pragma unroll
        for (int i = 0; i < 2; ++i) {
            const int r = w * 8 + i * 4 + quad;
            int g = s0 + r; if (g > M - 1) g = M - 1;
            const int sl = ln ^ (r & 15);               // inverse-swizzled slot
            gld_lds16(&rb[(size_t)g * D_DIM + sl * 8],
                      &Bt[half * (BR * D_DIM) + (w * 8 + i * 4) * D_DIM]);
        }
    };

    stage(0, 0);
    stage(1, nt > 1 ? 1 : 0);

    for (int it = 0; it < nt; ++it) {
        if (it + 1 < nt) asm volatile("s_waitcnt vmcnt(2)" ::: "memory");
        else             asm volatile("s_waitcnt vmcnt(0)" ::: "memory");
        __builtin_amdgcn_s_barrier();
        asm volatile("" ::: "memory");
        __builtin_amdgcn_sched_barrier(0);

        const int cur = it & 1;
        const unsigned short* Bc = &Bt[cur * (BR * D_DIM)];

        f32x16 acc0 = {0,0,0,0,0,0,0,0,0,0,0,0,0,0,0,0};
        f32x16 acc1 = {0,0,0,0,0,0,0,0,0,0,0,0,0,0,0,0};

        __builtin_amdgcn_s_setprio(1);
        #pragma unroll
        for (int ks = 0; ks < 8; ++ks) {
            const int sl = ((ks * 2 + hi) ^ ln) * 8;    // swizzled 16B slot
            bf16x8 a0 = *(const bf16x8*)&Bc[(l31)      * D_DIM + sl];
            bf16x8 a1 = *(const bf16x8*)&Bc[(32 + l31) * D_DIM + sl];
            acc0 = __builtin_amdgcn_mfma_f32_32x32x16_bf16(a0, qfr[ks], acc0, 0, 0, 0);
            acc1 = __builtin_amdgcn_mfma_f32_32x32x16_bf16(a1, qfr[ks], acc1, 0, 0, 0);
        }
        __builtin_amdgcn_s_setprio(0);

        // acc0/acc1 reg r = dot(q=row, ref = c0+it*64+{0,32}+crow),
        // crow = (r&3)+8*(r>>2)+4*hi  [m74/m101 verified layout].
        const int rem = clen - it * BR;
        if (rem >= BR) {
            #pragma unroll
            for (int r = 0; r < 16; ++r)
                mx[r] = fmaxf(mx[r], fmaxf(acc0[r], acc1[r]));
        } else {
            #pragma unroll
            for (int r = 0; r < 16; ++r) {
                const int crow = (r & 3) + 8 * (r >> 2) + 4 * hi;
                if (crow < rem)      mx[r] = fmaxf(mx[r], acc0[r]);
                if (32 + crow < rem) mx[r] = fmaxf(mx[r], acc1[r]);
            }
        }

        __builtin_amdgcn_sched_barrier(0);
        asm volatile("" ::: "memory");
        __builtin_amdgcn_s_barrier();
        if (it + 2 < nt) stage(cur, it + 2);
    }

    // hi-split subset write: subset s = by*32 + hi*16 + r.
    float* mp = &maxes[(size_t)row * NSUB + by * 32 + hi * 16];
    #pragma unroll
    for (int r4 = 0; r4 < 4; ++r4) {
        float4 v4 = { mx[r4 * 4], mx[r4 * 4 + 1], mx[r4 * 4 + 2], mx[r4 * 4 + 3] };
        *(float4*)&mp[r4 * 4] = v4;
    }
}

// Per-lane sorted top-(KK) slots, then kk+1 global max-extractions with
// static-shift pop (rule #20: no dynamic register indexing).
__device__ __forceinline__ float kth_largest_64(float* s, int kk, int lane) {
    float cur = -3.0f;
    for (int it = 0; it <= kk; ++it) {
        float m = s[0];
        #pragma unroll
        for (int off = 32; off > 0; off >>= 1) m = fmaxf(m, __shfl_xor(m, off));
        cur = m;
        unsigned long long b = __ballot(s[0] == m);
        bool owner = ((int)(__ffsll(b) - 1) == lane);
        #pragma unroll
        for (int j = 0; j < KK - 1; ++j) s[j] = owner ? s[j + 1] : s[j];
        if (owner) s[KK - 1] = -3.0f;
    }
    return cur;
}

// Fused per-row select: threshold + candidate gather + exact (k+1)-th.
__global__ __launch_bounds__(256) void knn_select(
    const unsigned short* __restrict__ zb, const unsigned short* __restrict__ rb,
    const float* __restrict__ maxes, const int* __restrict__ kp,
    float* __restrict__ out, int M, int chunk)
{
    const int row = blockIdx.x;
    const int t = threadIdx.x;
    __shared__ float dbuf[DNF];
    __shared__ int cand_s[NCAND];
    __shared__ int cn_s;

    const int kk = *kp;   // 10
    if (t == 0) cn_s = 0;

    // Phase A (wave 0): T = (kk+1)-th largest subset max; candidate append.
    if (t < 64) {
        float s[KK];
        #pragma unroll
        for (int j = 0; j < KK; ++j) s[j] = -3.0f;
        #pragma unroll
        for (int i = 0; i < NSUB / 64; ++i) {     // 32 coalesced loads
            float v = maxes[(size_t)row * NSUB + t + 64 * i];
            #pragma unroll
            for (int j = 0; j < KK; ++j) {        // descending sorted insert
                float hi = fmaxf(s[j], v), lo = fminf(s[j], v);
                s[j] = hi; v = lo;
            }
        }
        const float T = kth_largest_64(s, kk, t);
        #pragma unroll
        for (int i = 0; i < NSUB / 64; ++i) {     // reload (L1-hot); append
            float v = maxes[(size_t)row * NSUB + t + 64 * i];
            if (v >= T) {
                int sl = atomicAdd(&cn_s, 1);
                if (sl < NCAND) cand_s[sl] = t + 64 * i;
            }
        }
    }

    // Meanwhile (all waves): q slice into regs.  Lane gl covers elements
    // [gl*8, gl*8+8) and [64+gl*8, 64+gl*8+8) -- the 8-lane group jointly
    // covers all 128.
    const int gl = t & 7;
    const int grp = t >> 3;                       // 0..31 groups per block
    float q0r[8], q1r[8];
    {
        bf16x8 qv0 = *(const bf16x8*)&zb[(size_t)row * D_DIM + gl * 8];
        bf16x8 qv1 = *(const bf16x8*)&zb[(size_t)row * D_DIM + 64 + gl * 8];
        #pragma unroll
        for (int e = 0; e < 8; ++e) { q0r[e] = (float)qv0[e]; q1r[e] = (float)qv1[e]; }
    }
    __syncthreads();

    const int cn = cn_s;
    const int slots = ((chunk + 63) >> 6) * 2;    // tiles x {0,32}; 26 here
    int nsel;

    if (cn <= NCAND && slots <= SLOTS) {
        // Normal path: recompute candidate subsets' dots cooperatively.
        const int W = cn * slots;                 // <= 832 live slots
        for (int i = t; i < W; i += 256) dbuf[i] = -3.0f;
        __syncthreads();
        for (int ci = 0; ci < cn; ++ci) {
            const int s  = cand_s[ci];
            const int by = s >> 5;
            const int h2 = (s >> 4) & 1;
            const int r  = s & 15;
            const int base = (r & 3) + 8 * (r >> 2) + 4 * h2;
            const int c0 = by * chunk;
            const int c1 = min(c0 + chunk, M);
            for (int sl = grp; sl < slots; sl += 32) {
                const int ref = c0 + (sl >> 1) * 64 + (sl & 1) * 32 + base;
                const bool valid = ref < c1;
                float p = 0.f;
                if (valid) {
                    const unsigned short* rp = &rb[(size_t)ref * D_DIM + gl * 8];
                    bf16x8 r0 = *(const bf16x8*)rp;          // coalesced 128B
                    bf16x8 r1 = *(const bf16x8*)(rp + 64);   // per 8-lane group
                    #pragma unroll
                    for (int e = 0; e < 8; ++e) {
                        p = fmaf((float)r0[e], q0r[e], p);
                        p = fmaf((float)r1[e], q1r[e], p);
                    }
                }
                p += __shfl_xor(p, 1);            // butterfly: all 8 lanes
                p += __shfl_xor(p, 2);            // end with the full dot
                p += __shfl_xor(p, 4);
                if (gl == 0 && valid) dbuf[ci * slots + sl] = p;
            }
        }
        nsel = W;
    } else {
        // Tie-overflow fallback (~never): exact full scan of this row.
        // Groups stride the refs; butterfly gives every lane the dot; each
        // thread keeps its own top-KK (redundant x8, correct).
        float s[KK];
        #pragma unroll
        for (int j = 0; j < KK; ++j) s[j] = -3.0f;
        for (int g = grp; g < M; g += 32) {
            const unsigned short* rp = &rb[(size_t)g * D_DIM + gl * 8];
            bf16x8 r0 = *(const bf16x8*)rp;
            bf16x8 r1 = *(const bf16x8*)(rp + 64);
            float p = 0.f;
            #pragma unroll
            for (int e = 0; e < 8; ++e) {
                p = fmaf((float)r0[e], q0r[e], p);
                p = fmaf((float)r1[e], q1r[e], p);
            }
            p += __shfl_xor(p, 1);
            p += __shfl_xor(p, 2);
            p += __shfl_xor(p, 4);
            #pragma unroll
            for (int j = 0; j < KK; ++j) {
                float hi = fmaxf(s[j], p), lo = fminf(s[j], p);
                s[j] = hi; p = lo;
            }
        }
        #pragma unroll
        for (int j = 0; j < KK; ++j) dbuf[t * KK + j] = s[j];   // 256*11 = DNF
        nsel = DNF;
    }
    __syncthreads();

    // Final: (kk+1)-th largest over the live dbuf range (wave 0).
    if (t < 64) {
        float s[KK];
        #pragma unroll
        for (int j = 0; j < KK; ++j) s[j] = -3.0f;
        for (int j = t; j < nsel; j += 64) {      // ~5 rounds normal path
            float v = dbuf[j];
            #pragma unroll
            for (int q = 0; q < KK; ++q) {
                float hi = fmaxf(s[q], v), lo = fminf(s[q], v);
                s[q] = hi; v = lo;
            }
        }
        const float cur = kth_largest_64(s, kk, t);
        if (t == 0) out[row] = sqrtf(fmaxf(2.0f - 2.0f * cur, 1e-12f));
    }
}

extern "C" void kernel_launch(void* const* d_in, const int* in_sizes, int n_in,
                              void* d_out, int out_size, void* d_ws, size_t ws_size,
                              hipStream_t stream) {
    const float* z   = (const float*)d_in[0];
    const float* ref = (const float*)d_in[1];
    const int*   kp  = (const int*)d_in[2];
    float* out = (float*)d_out;

    const int N = in_sizes[0] / D_DIM;   // 2048
    const int M = in_sizes[1] / D_DIM;   // 50000

    unsigned short* zbuf = (unsigned short*)d_ws;             // N*128 bf16
    unsigned short* rbuf = zbuf + (size_t)N * D_DIM;          // M*128 bf16
    float* maxes = (float*)(rbuf + (size_t)M * D_DIM);        // N*NSUB f32 (16MB)

    normalize_bf16<<<(N + M + 3) / 4, 256, 0, stream>>>(z, ref, zbuf, rbuf, N, M);

    const int chunk = (M + NCH - 1) / NCH;    // 782
    dim3 grid(N / TQB, NCH);                  // 8 x 64 = 512 blocks

    knn_maxes<<<grid, 512, 0, stream>>>(zbuf, rbuf, maxes, N, M, chunk);
    knn_select<<<N, 256, 0, stream>>>(zbuf, rbuf, maxes, kp, out, M, chunk);
}